// Round 7
// baseline (345.483 us; speedup 1.0000x reference)
//
#include <hip/hip_runtime.h>
#include <hip/hip_bf16.h>
#include <cmath>

#define BETA 0.3f
#define LAMBDA_PHY 0.15f

#define BM 256
#define BN 256
#define BK 64
#define NT 512

typedef __bf16 bf16x8 __attribute__((ext_vector_type(8)));
typedef float f32x4 __attribute__((ext_vector_type(4)));

#define AS1 __attribute__((address_space(1)))
#define AS3 __attribute__((address_space(3)))

#define FENCE() asm volatile("" ::: "memory")
#define BARRIER() do { FENCE(); __builtin_amdgcn_s_barrier(); FENCE(); } while (0)
#define WAITV8() asm volatile("s_waitcnt vmcnt(8)" ::: "memory")
#define WAITV0() asm volatile("s_waitcnt vmcnt(0)" ::: "memory")

__device__ __forceinline__ unsigned short f2bf_rn(float f) {
    unsigned int u = __builtin_bit_cast(unsigned int, f);
    return (unsigned short)((u + 0x7FFFu + ((u >> 16) & 1u)) >> 16);
}

__device__ __forceinline__ float bf2f(unsigned short u) {
    return __builtin_bit_cast(float, (unsigned int)u << 16);
}

__device__ __forceinline__ float softplus_f(float x) {
    return fmaxf(x, 0.0f) + __logf(1.0f + __expf(-fabsf(x)));
}

__device__ __forceinline__ float smooth_l1_f(float d) {
    float ad = fabsf(d);
    return (ad < BETA) ? (0.5f / BETA) * d * d : (ad - 0.5f * BETA);
}

// ---------------------------------------------------------------------------
// Kernel 1: adjacency (int32 ZxZ) -> bf16 mask (ZxZ, K-contig) + invdeg + hasnb
__global__ void k_prep(const int* __restrict__ adj, unsigned short* __restrict__ maskbf,
                       float* __restrict__ invdeg, float* __restrict__ hasnb, int Z) {
    int z = blockIdx.x;
    int t = threadIdx.x;
    const int* row = adj + (size_t)z * Z;
    unsigned short* mrow = maskbf + (size_t)z * Z;
    int cnt = 0;
    for (int n = t; n < Z; n += blockDim.x) {
        int a = (row[n] > 0);
        mrow[n] = a ? (unsigned short)0x3F80 : (unsigned short)0;  // bf16 1.0 / 0.0
        cnt += a;
    }
    for (int o = 32; o; o >>= 1) cnt += __shfl_down(cnt, o);
    __shared__ int rs[4];
    int lane = t & 63, wave = t >> 6;
    if (lane == 0) rs[wave] = cnt;
    __syncthreads();
    if (t == 0) {
        int deg = rs[0] + rs[1] + rs[2] + rs[3];
        invdeg[z] = (deg > 0) ? 1.0f / (float)deg : 1.0f;
        hasnb[z]  = (deg > 0) ? 1.0f : 0.0f;
    }
}

// ---------------------------------------------------------------------------
// Kernel 2: fp32 -> bf16 (RN), 8 elems/thread, vectorized
__global__ void k_conv(const float* __restrict__ src, uint4* __restrict__ dst, long n8) {
    long i = (long)blockIdx.x * blockDim.x + threadIdx.x;
    long stride = (long)gridDim.x * blockDim.x;
    for (; i < n8; i += stride) {
        const float4* s = (const float4*)(src + i * 8);
        float4 a = s[0], b = s[1];
        uint4 o;
        o.x = (unsigned)f2bf_rn(a.x) | ((unsigned)f2bf_rn(a.y) << 16);
        o.y = (unsigned)f2bf_rn(a.z) | ((unsigned)f2bf_rn(a.w) << 16);
        o.z = (unsigned)f2bf_rn(b.x) | ((unsigned)f2bf_rn(b.y) << 16);
        o.w = (unsigned)f2bf_rn(b.z) | ((unsigned)f2bf_rn(b.w) << 16);
        dst[i] = o;
    }
}

// ---------------------------------------------------------------------------
// Kernel 3: 256x256 bf16 GEMM, 8 waves (2x4, 128x64 out each).
// 2-phase tile loop, spill-free by design:
//   - STAGE next tile (8 global_load_lds/thread) at tile top into nb
//   - vmcnt(8): waits only PREVIOUS tile's loads (issued one full compute
//     tile ago ~1500cyc slack) -> counted, never drains in-loop
//   - barrier; compute cur (af[4][2] per A-half, bv[2][2] per 32-col pair);
//     barrier (protects nb from next stage)
// Arch live-set ~115 regs < 128 (acc[8][4]=128 AGPR at 2 waves/SIMD budget).
// T2 XOR swizzle (pre-swizzled source col + same XOR on reads), T1 XCD swizzle.
__global__ __launch_bounds__(NT) void k_gemm(
    const unsigned short* __restrict__ Abf,   // [M][K] bf16 ctemps
    const unsigned short* __restrict__ Bbf,   // [N][K] bf16 mask
    const float* __restrict__ preds,
    const float* __restrict__ targets,
    const float* __restrict__ invdeg,
    const float* __restrict__ hasnb,
    float* __restrict__ partials,
    int M, int N, int K)
{
    __shared__ unsigned short As[2][256 * 64];   // [buf][row*64 + col]
    __shared__ unsigned short Bs[2][256 * 64];

    const int nwg = gridDim.x;
    const int ob = blockIdx.x;
    const int bid = (nwg % 8 == 0) ? ((ob % 8) * (nwg / 8) + ob / 8) : ob;  // T1
    const int ntiles = N / BN;
    const int mt = bid / ntiles;
    const int nt = bid % ntiles;
    const int row0 = mt * BM;
    const int col0 = nt * BN;
    const int t = threadIdx.x;
    const int lane = t & 63;
    const int wave = t >> 6;
    const int wm = wave >> 2;             // 2x4 wave grid; per-wave 128x64 out
    const int wn = wave & 3;
    const int fr = lane & 15;
    const int fq = lane >> 4;
    const int fr7 = fr & 7;

    // staging: thread t -> row tr (+64 per load), 16B slot tc; source col-slot
    // pre-swizzled. LDS dest is t-linear (t*16 B) = wave-uniform + lane*16. ✓
    const int tr = t >> 3;                // 0..63
    const int tc = t & 7;                 // 16B slot 0..7
    const int cs = tc ^ (tr & 7);         // swizzled global col-slot

    f32x4 acc[8][4];
#pragma unroll
    for (int m = 0; m < 8; ++m)
#pragma unroll
        for (int n = 0; n < 4; ++n)
            acc[m][n] = (f32x4){0.f, 0.f, 0.f, 0.f};

    // per-thread source pointers (advance by BK per tile)
    const unsigned short* aSrc = Abf + (size_t)(row0 + tr) * K + cs * 8;
    const unsigned short* bSrc = Bbf + (size_t)(col0 + tr) * K + cs * 8;
    unsigned short* aDst = &As[0][t * 8];   // t*16 bytes
    unsigned short* bDst = &Bs[0][t * 8];

#define STAGE8(nbuf) do {                                                                    \
    unsigned short* ad_ = aDst + (nbuf) * 16384;                                             \
    unsigned short* bd_ = bDst + (nbuf) * 16384;                                             \
    _Pragma("unroll")                                                                        \
    for (int r_ = 0; r_ < 4; ++r_)                                                           \
        __builtin_amdgcn_global_load_lds((const AS1 void*)(aSrc + (size_t)(r_ * 64) * K),    \
                                         (AS3 void*)(ad_ + r_ * 4096), 16, 0, 0);            \
    _Pragma("unroll")                                                                        \
    for (int r_ = 0; r_ < 4; ++r_)                                                           \
        __builtin_amdgcn_global_load_lds((const AS1 void*)(bSrc + (size_t)(r_ * 64) * K),    \
                                         (AS3 void*)(bd_ + r_ * 4096), 16, 0, 0);            \
} while (0)

    bf16x8 af[4][2];   // A frags of current A-half: [mi][kk]  (64 VGPR)
    bf16x8 bv[2][2];   // B frags of current 32-col pair: [ni][kk] (32 VGPR)

#define LOAD_AF(buf, mq) do {                                                                \
    _Pragma("unroll")                                                                        \
    for (int mi_ = 0; mi_ < 4; ++mi_)                                                        \
    _Pragma("unroll")                                                                        \
    for (int kk_ = 0; kk_ < 2; ++kk_)                                                        \
        af[mi_][kk_] = *(const bf16x8*)&As[buf][(wm * 128 + (mq) * 64 + mi_ * 16 + fr) * 64 +\
                                               (((kk_ * 4 + fq) ^ fr7) * 8)];                \
} while (0)

#define LOAD_BV(buf, nq) do {                                                                \
    _Pragma("unroll")                                                                        \
    for (int ni_ = 0; ni_ < 2; ++ni_)                                                        \
    _Pragma("unroll")                                                                        \
    for (int kk_ = 0; kk_ < 2; ++kk_)                                                        \
        bv[ni_][kk_] = *(const bf16x8*)&Bs[buf][(wn * 64 + (nq) * 32 + ni_ * 16 + fr) * 64 + \
                                               (((kk_ * 4 + fq) ^ fr7) * 8)];                \
} while (0)

#define MFMA_Q(mq, nq) do {                                                                  \
    _Pragma("unroll")                                                                        \
    for (int kk_ = 0; kk_ < 2; ++kk_)                                                        \
    _Pragma("unroll")                                                                        \
    for (int mi_ = 0; mi_ < 4; ++mi_)                                                        \
    _Pragma("unroll")                                                                        \
    for (int ni_ = 0; ni_ < 2; ++ni_)                                                        \
        acc[(mq) * 4 + mi_][(nq) * 2 + ni_] = __builtin_amdgcn_mfma_f32_16x16x32_bf16(       \
            af[mi_][kk_], bv[ni_][kk_], acc[(mq) * 4 + mi_][(nq) * 2 + ni_], 0, 0, 0);       \
} while (0)

    const int nk = K / BK;
    STAGE8(0);                       // tile 0 -> buf 0
    aSrc += BK; bSrc += BK;

    int cur = 0;
    for (int ti = 0; ti < nk; ++ti) {
        if (ti + 1 < nk) {
            STAGE8(cur ^ 1);         // tile ti+1 -> nb (nb free: barrier#2 of ti-1)
            aSrc += BK; bSrc += BK;
            WAITV8();                // retires tile ti's 8 loads (oldest in FIFO)
        } else {
            WAITV0();
        }
        BARRIER();                   // collective: cur fully staged for all waves
#pragma unroll
        for (int mq = 0; mq < 2; ++mq) {
            LOAD_AF(cur, mq);
#pragma unroll
            for (int nq = 0; nq < 2; ++nq) {
                LOAD_BV(cur, nq);
                MFMA_Q(mq, nq);
            }
        }
        BARRIER();                   // all reads of cur done before next stage
        cur ^= 1;
    }

#undef STAGE8
#undef LOAD_AF
#undef LOAD_BV
#undef MFMA_Q

    // Fused epilogue. C/D frag layout: col=lane&15, row=(lane>>4)*4+reg.
    // block row = wm*128 + m*16 + fq*4 + j ; block col = wn*64 + n*16 + fr
    float vsum = 0.f, ssum = 0.f;
#pragma unroll
    for (int n = 0; n < 4; ++n) {
        const int z = col0 + wn * 64 + n * 16 + fr;
        const float idg = invdeg[z];
        const float hnb = hasnb[z];
#pragma unroll
        for (int m = 0; m < 8; ++m) {
            const int rb = row0 + wm * 128 + m * 16 + fq * 4;
#pragma unroll
            for (int j = 0; j < 4; ++j) {
                const size_t idx = (size_t)(rb + j) * N + z;
                float avg = acc[m][n][j] * idg;
                float c = bf2f(Abf[idx]);          // bf16 ctemps (saves 1/3 fetch)
                float p = preds[idx];
                float tg = targets[idx];
                float x = (c - avg) * (p - c);
                vsum += softplus_f(x) * hnb;
                ssum += smooth_l1_f(p - tg);
            }
        }
    }
    for (int o = 32; o; o >>= 1) { vsum += __shfl_down(vsum, o); ssum += __shfl_down(ssum, o); }
    __shared__ float rv[8], rsm[8];
    if (lane == 0) { rv[wave] = vsum; rsm[wave] = ssum; }
    __syncthreads();
    if (t == 0) {
        float v = 0.f, s = 0.f;
#pragma unroll
        for (int w = 0; w < 8; ++w) { v += rv[w]; s += rsm[w]; }
        partials[2 * (size_t)ob]     = v;
        partials[2 * (size_t)ob + 1] = s;
    }
}

// ---------------------------------------------------------------------------
// Kernel 4: deterministic fixed-order final reduction
__global__ void k_finalize(const float* __restrict__ partials, int nblk,
                           float* __restrict__ out, float invBZ) {
    __shared__ float sv[256], ss[256];
    int t = threadIdx.x;
    float v = 0.f, s = 0.f;
    for (int i = t; i < nblk; i += 256) { v += partials[2 * (size_t)i]; s += partials[2 * (size_t)i + 1]; }
    sv[t] = v; ss[t] = s;
    __syncthreads();
    for (int o = 128; o; o >>= 1) {
        if (t < o) { sv[t] += sv[t + o]; ss[t] += ss[t + o]; }
        __syncthreads();
    }
    if (t == 0) {
        float phys = sv[0] * invBZ;
        float pred = ss[0] * invBZ;
        out[0] = pred + LAMBDA_PHY * phys;
        out[1] = phys;
    }
}

// ---------------------------------------------------------------------------
// Fallback path (only if ws too small / odd shapes): fp32, atomics into ws[0..1]
__global__ void k_zero2(float* p) { if (threadIdx.x < 2) p[threadIdx.x] = 0.f; }

__global__ void k_fallback(const float* __restrict__ preds, const float* __restrict__ targets,
                           const float* __restrict__ ctemps, const int* __restrict__ adj,
                           float* __restrict__ acc2, int B, int Z) {
    extern __shared__ float crow[];
    int nzb = (Z + 255) / 256;
    int b = blockIdx.x / nzb;
    int zb = blockIdx.x % nzb;
    int t = threadIdx.x;
    const float* cr = ctemps + (size_t)b * Z;
    for (int n = t; n < Z; n += 256) crow[n] = cr[n];
    __syncthreads();
    int z = zb * 256 + t;
    float vsum = 0.f, ssum = 0.f;
    if (z < Z) {
        const int* arow = adj + (size_t)z * Z;
        float sum = 0.f; int deg = 0;
        for (int n = 0; n < Z; ++n) {
            if (arow[n] > 0) { sum += crow[n]; ++deg; }
        }
        float avg = (deg > 0) ? sum / (float)deg : 0.f;
        float c = crow[z];
        size_t idx = (size_t)b * Z + z;
        float p = preds[idx];
        float x = (c - avg) * (p - c);
        vsum = (deg > 0) ? softplus_f(x) : 0.f;
        ssum = smooth_l1_f(p - targets[idx]);
    }
    for (int o = 32; o; o >>= 1) { vsum += __shfl_down(vsum, o); ssum += __shfl_down(ssum, o); }
    __shared__ float rv[4], rs2[4];
    int lane = t & 63, wave = t >> 6;
    if (lane == 0) { rv[wave] = vsum; rs2[wave] = ssum; }
    __syncthreads();
    if (t == 0) {
        atomicAdd(&acc2[0], rv[0] + rv[1] + rv[2] + rv[3]);
        atomicAdd(&acc2[1], rs2[0] + rs2[1] + rs2[2] + rs2[3]);
    }
}

// ---------------------------------------------------------------------------
extern "C" void kernel_launch(void* const* d_in, const int* in_sizes, int n_in,
                              void* d_out, int out_size, void* d_ws, size_t ws_size,
                              hipStream_t stream) {
    const float* preds   = (const float*)d_in[0];
    const float* targets = (const float*)d_in[1];
    const float* ctemps  = (const float*)d_in[2];
    const int*   adj     = (const int*)d_in[3];
    float* out = (float*)d_out;

    long zz = in_sizes[3];
    int Z = (int)llround(sqrt((double)zz));
    int B = in_sizes[1] / Z;

    size_t off = 0;
    size_t maskOff = off; off += (size_t)Z * Z * 2;
    size_t cbfOff  = off; off += (size_t)B * Z * 2;
    size_t idgOff  = off; off += (size_t)Z * 4;
    size_t hnbOff  = off; off += (size_t)Z * 4;
    int nblk = (Z > 0 && B > 0 && (B % BM) == 0 && (Z % BN) == 0) ? (B / BM) * (Z / BN) : 0;
    size_t partOff = off; off += (size_t)(nblk > 0 ? nblk : 1) * 2 * 4;

    bool main_ok = (B % BM == 0) && (Z % BN == 0) && (Z % BK == 0) && (ws_size >= off);

    float invBZ = (float)(1.0 / ((double)B * (double)Z));

    if (main_ok) {
        char* ws = (char*)d_ws;
        unsigned short* maskbf = (unsigned short*)(ws + maskOff);
        unsigned short* cbf    = (unsigned short*)(ws + cbfOff);
        float* idg      = (float*)(ws + idgOff);
        float* hnb      = (float*)(ws + hnbOff);
        float* partials = (float*)(ws + partOff);

        k_prep<<<Z, 256, 0, stream>>>(adj, maskbf, idg, hnb, Z);
        long n8 = (long)B * Z / 8;
        k_conv<<<2048, 256, 0, stream>>>(ctemps, (uint4*)cbf, n8);
        k_gemm<<<nblk, NT, 0, stream>>>(cbf, maskbf, preds, targets, idg, hnb, partials, B, Z, Z);
        k_finalize<<<1, 256, 0, stream>>>(partials, nblk, out, invBZ);
    } else {
        float* acc2 = (float*)d_ws;
        k_zero2<<<1, 64, 0, stream>>>(acc2);
        int nzb = (Z + 255) / 256;
        k_fallback<<<B * nzb, 256, (size_t)Z * 4, stream>>>(preds, targets, ctemps, adj, acc2, B, Z);
        k_finalize<<<1, 256, 0, stream>>>(acc2, 1, out, invBZ);
    }
}

// Round 8
// 252.932 us; speedup vs baseline: 1.3659x; 1.3659x over previous
//
#include <hip/hip_runtime.h>
#include <hip/hip_bf16.h>
#include <cmath>

#define BETA 0.3f
#define LAMBDA_PHY 0.15f

#define BM 128
#define BN 256
#define BK 64
#define NT 512

typedef __bf16 bf16x8 __attribute__((ext_vector_type(8)));
typedef float f32x4 __attribute__((ext_vector_type(4)));

#define AS1 __attribute__((address_space(1)))
#define AS3 __attribute__((address_space(3)))

#define FENCE() asm volatile("" ::: "memory")
#define BARRIER() do { FENCE(); __builtin_amdgcn_s_barrier(); FENCE(); } while (0)
#define WAITV6() asm volatile("s_waitcnt vmcnt(6)" ::: "memory")
#define WAITV0() asm volatile("s_waitcnt vmcnt(0)" ::: "memory")

__device__ __forceinline__ unsigned short f2bf_rn(float f) {
    unsigned int u = __builtin_bit_cast(unsigned int, f);
    return (unsigned short)((u + 0x7FFFu + ((u >> 16) & 1u)) >> 16);
}

__device__ __forceinline__ float bf2f(unsigned short u) {
    return __builtin_bit_cast(float, (unsigned int)u << 16);
}

__device__ __forceinline__ float softplus_f(float x) {
    return fmaxf(x, 0.0f) + __logf(1.0f + __expf(-fabsf(x)));
}

__device__ __forceinline__ float smooth_l1_f(float d) {
    float ad = fabsf(d);
    return (ad < BETA) ? (0.5f / BETA) * d * d : (ad - 0.5f * BETA);
}

// ---------------------------------------------------------------------------
// Kernel 1: adjacency (int32 ZxZ) -> bf16 mask (ZxZ, K-contig) + invdeg + hasnb
__global__ void k_prep(const int* __restrict__ adj, unsigned short* __restrict__ maskbf,
                       float* __restrict__ invdeg, float* __restrict__ hasnb, int Z) {
    int z = blockIdx.x;
    int t = threadIdx.x;
    const int* row = adj + (size_t)z * Z;
    unsigned short* mrow = maskbf + (size_t)z * Z;
    int cnt = 0;
    for (int n = t; n < Z; n += blockDim.x) {
        int a = (row[n] > 0);
        mrow[n] = a ? (unsigned short)0x3F80 : (unsigned short)0;  // bf16 1.0 / 0.0
        cnt += a;
    }
    for (int o = 32; o; o >>= 1) cnt += __shfl_down(cnt, o);
    __shared__ int rs[4];
    int lane = t & 63, wave = t >> 6;
    if (lane == 0) rs[wave] = cnt;
    __syncthreads();
    if (t == 0) {
        int deg = rs[0] + rs[1] + rs[2] + rs[3];
        invdeg[z] = (deg > 0) ? 1.0f / (float)deg : 1.0f;
        hasnb[z]  = (deg > 0) ? 1.0f : 0.0f;
    }
}

// ---------------------------------------------------------------------------
// Kernel 2: fp32 -> bf16 (RN), 8 elems/thread, vectorized
__global__ void k_conv(const float* __restrict__ src, uint4* __restrict__ dst, long n8) {
    long i = (long)blockIdx.x * blockDim.x + threadIdx.x;
    long stride = (long)gridDim.x * blockDim.x;
    for (; i < n8; i += stride) {
        const float4* s = (const float4*)(src + i * 8);
        float4 a = s[0], b = s[1];
        uint4 o;
        o.x = (unsigned)f2bf_rn(a.x) | ((unsigned)f2bf_rn(a.y) << 16);
        o.y = (unsigned)f2bf_rn(a.z) | ((unsigned)f2bf_rn(a.w) << 16);
        o.z = (unsigned)f2bf_rn(b.x) | ((unsigned)f2bf_rn(b.y) << 16);
        o.w = (unsigned)f2bf_rn(b.z) | ((unsigned)f2bf_rn(b.w) << 16);
        dst[i] = o;
    }
}

// ---------------------------------------------------------------------------
// Kernel 3: 128x256 bf16 GEMM, 8 waves (2x4), per-wave 64x64 output.
// Register identity (rounds 2-7): at NT=512 the allocator gives 256 unified
// regs/wave = acc(AGPR) + 128 arch cap. acc must be <=64 for the arch
// live-set to fit -> per-wave 64x64 output (acc[4][4]=64), af 32 + bv 32
// + addressing ~90 arch. No spill by construction (round-1 pattern).
// 2-phase tile loop, counted vmcnt(6) (full-tile issue-to-wait slack),
// raw barriers, T2 XOR swizzle, T1 bijective XCD swizzle.
__global__ __launch_bounds__(NT) void k_gemm(
    const unsigned short* __restrict__ Abf,   // [M][K] bf16 ctemps
    const unsigned short* __restrict__ Bbf,   // [N][K] bf16 mask
    const float* __restrict__ preds,
    const float* __restrict__ targets,
    const float* __restrict__ invdeg,
    const float* __restrict__ hasnb,
    float* __restrict__ partials,
    int M, int N, int K)
{
    __shared__ unsigned short As[2][BM * 64];   // 32 KB
    __shared__ unsigned short Bs[2][BN * 64];   // 64 KB

    const int nwg = gridDim.x;
    const int ob = blockIdx.x;
    const int bid = (nwg % 8 == 0) ? ((ob % 8) * (nwg / 8) + ob / 8) : ob;  // T1
    const int ntiles = N / BN;
    const int mt = bid / ntiles;
    const int nt = bid % ntiles;
    const int row0 = mt * BM;
    const int col0 = nt * BN;
    const int t = threadIdx.x;
    const int lane = t & 63;
    const int wave = t >> 6;
    const int wm = wave >> 2;             // 2x4 wave grid; per-wave 64x64 out
    const int wn = wave & 3;
    const int fr = lane & 15;
    const int fq = lane >> 4;
    const int fr7 = fr & 7;

    // staging: thread t -> row tr (+64 per chunk), 16B slot tc; source col-slot
    // pre-swizzled (T2). LDS dest is t-linear (t*16 B). A: 2 chunks, B: 4.
    const int tr = t >> 3;                // 0..63
    const int tc = t & 7;                 // 16B slot 0..7
    const int cs = tc ^ (tr & 7);         // swizzled global col-slot

    f32x4 acc[4][4];
#pragma unroll
    for (int m = 0; m < 4; ++m)
#pragma unroll
        for (int n = 0; n < 4; ++n)
            acc[m][n] = (f32x4){0.f, 0.f, 0.f, 0.f};

    // per-thread source pointers (advance by BK per tile)
    const unsigned short* aSrc = Abf + (size_t)(row0 + tr) * K + cs * 8;
    const unsigned short* bSrc = Bbf + (size_t)(col0 + tr) * K + cs * 8;
    unsigned short* aDst = &As[0][t * 8];   // t*16 bytes
    unsigned short* bDst = &Bs[0][t * 8];

#define STAGE6(nbuf) do {                                                                    \
    unsigned short* ad_ = aDst + (nbuf) * (BM * 64);                                         \
    unsigned short* bd_ = bDst + (nbuf) * (BN * 64);                                         \
    _Pragma("unroll")                                                                        \
    for (int r_ = 0; r_ < 2; ++r_)                                                           \
        __builtin_amdgcn_global_load_lds((const AS1 void*)(aSrc + (size_t)(r_ * 64) * K),    \
                                         (AS3 void*)(ad_ + r_ * 4096), 16, 0, 0);            \
    _Pragma("unroll")                                                                        \
    for (int r_ = 0; r_ < 4; ++r_)                                                           \
        __builtin_amdgcn_global_load_lds((const AS1 void*)(bSrc + (size_t)(r_ * 64) * K),    \
                                         (AS3 void*)(bd_ + r_ * 4096), 16, 0, 0);            \
} while (0)

    bf16x8 af[4][2];   // A frags of wave's 64 rows: [mi][kk]  (32 VGPR)
    bf16x8 bv[4][2];   // B frags of wave's 64 cols: [ni][kk]  (32 VGPR)

#define LOAD_AF(buf) do {                                                                    \
    _Pragma("unroll")                                                                        \
    for (int mi_ = 0; mi_ < 4; ++mi_)                                                        \
    _Pragma("unroll")                                                                        \
    for (int kk_ = 0; kk_ < 2; ++kk_)                                                        \
        af[mi_][kk_] = *(const bf16x8*)&As[buf][(wm * 64 + mi_ * 16 + fr) * 64 +             \
                                               (((kk_ * 4 + fq) ^ fr7) * 8)];                \
} while (0)

#define LOAD_BV(buf) do {                                                                    \
    _Pragma("unroll")                                                                        \
    for (int ni_ = 0; ni_ < 4; ++ni_)                                                        \
    _Pragma("unroll")                                                                        \
    for (int kk_ = 0; kk_ < 2; ++kk_)                                                        \
        bv[ni_][kk_] = *(const bf16x8*)&Bs[buf][(wn * 64 + ni_ * 16 + fr) * 64 +             \
                                               (((kk_ * 4 + fq) ^ fr7) * 8)];                \
} while (0)

#define MFMA_T() do {                                                                        \
    _Pragma("unroll")                                                                        \
    for (int kk_ = 0; kk_ < 2; ++kk_)                                                        \
    _Pragma("unroll")                                                                        \
    for (int mi_ = 0; mi_ < 4; ++mi_)                                                        \
    _Pragma("unroll")                                                                        \
    for (int ni_ = 0; ni_ < 4; ++ni_)                                                        \
        acc[mi_][ni_] = __builtin_amdgcn_mfma_f32_16x16x32_bf16(                             \
            af[mi_][kk_], bv[ni_][kk_], acc[mi_][ni_], 0, 0, 0);                             \
} while (0)

    const int nk = K / BK;
    STAGE6(0);                       // tile 0 -> buf 0
    aSrc += BK; bSrc += BK;

    int cur = 0;
    for (int ti = 0; ti < nk; ++ti) {
        if (ti + 1 < nk) {
            STAGE6(cur ^ 1);         // tile ti+1 -> nb (nb free since barrier#2 of ti-1)
            aSrc += BK; bSrc += BK;
            WAITV6();                // retires tile ti's 6 loads (oldest in FIFO)
        } else {
            WAITV0();
        }
        BARRIER();                   // collective: cur fully staged for all waves
        LOAD_AF(cur);
        LOAD_BV(cur);
        MFMA_T();
        BARRIER();                   // all reads of cur done before next stage
        cur ^= 1;
    }

#undef STAGE6
#undef LOAD_AF
#undef LOAD_BV
#undef MFMA_T

    // Fused epilogue. C/D frag layout: col=lane&15, row=(lane>>4)*4+reg.
    // block row = wm*64 + m*16 + fq*4 + j ; block col = wn*64 + n*16 + fr
    float vsum = 0.f, ssum = 0.f;
#pragma unroll
    for (int n = 0; n < 4; ++n) {
        const int z = col0 + wn * 64 + n * 16 + fr;
        const float idg = invdeg[z];
        const float hnb = hasnb[z];
#pragma unroll
        for (int m = 0; m < 4; ++m) {
            const int rb = row0 + wm * 64 + m * 16 + fq * 4;
#pragma unroll
            for (int j = 0; j < 4; ++j) {
                const size_t idx = (size_t)(rb + j) * N + z;
                float avg = acc[m][n][j] * idg;
                float c = bf2f(Abf[idx]);          // bf16 ctemps (saves 1/3 fetch)
                float p = preds[idx];
                float tg = targets[idx];
                float x = (c - avg) * (p - c);
                vsum += softplus_f(x) * hnb;
                ssum += smooth_l1_f(p - tg);
            }
        }
    }
    for (int o = 32; o; o >>= 1) { vsum += __shfl_down(vsum, o); ssum += __shfl_down(ssum, o); }
    __shared__ float rv[8], rsm[8];
    if (lane == 0) { rv[wave] = vsum; rsm[wave] = ssum; }
    __syncthreads();
    if (t == 0) {
        float v = 0.f, s = 0.f;
#pragma unroll
        for (int w = 0; w < 8; ++w) { v += rv[w]; s += rsm[w]; }
        partials[2 * (size_t)ob]     = v;
        partials[2 * (size_t)ob + 1] = s;
    }
}

// ---------------------------------------------------------------------------
// Kernel 4: deterministic fixed-order final reduction
__global__ void k_finalize(const float* __restrict__ partials, int nblk,
                           float* __restrict__ out, float invBZ) {
    __shared__ float sv[256], ss[256];
    int t = threadIdx.x;
    float v = 0.f, s = 0.f;
    for (int i = t; i < nblk; i += 256) { v += partials[2 * (size_t)i]; s += partials[2 * (size_t)i + 1]; }
    sv[t] = v; ss[t] = s;
    __syncthreads();
    for (int o = 128; o; o >>= 1) {
        if (t < o) { sv[t] += sv[t + o]; ss[t] += ss[t + o]; }
        __syncthreads();
    }
    if (t == 0) {
        float phys = sv[0] * invBZ;
        float pred = ss[0] * invBZ;
        out[0] = pred + LAMBDA_PHY * phys;
        out[1] = phys;
    }
}

// ---------------------------------------------------------------------------
// Fallback path (only if ws too small / odd shapes): fp32, atomics into ws[0..1]
__global__ void k_zero2(float* p) { if (threadIdx.x < 2) p[threadIdx.x] = 0.f; }

__global__ void k_fallback(const float* __restrict__ preds, const float* __restrict__ targets,
                           const float* __restrict__ ctemps, const int* __restrict__ adj,
                           float* __restrict__ acc2, int B, int Z) {
    extern __shared__ float crow[];
    int nzb = (Z + 255) / 256;
    int b = blockIdx.x / nzb;
    int zb = blockIdx.x % nzb;
    int t = threadIdx.x;
    const float* cr = ctemps + (size_t)b * Z;
    for (int n = t; n < Z; n += 256) crow[n] = cr[n];
    __syncthreads();
    int z = zb * 256 + t;
    float vsum = 0.f, ssum = 0.f;
    if (z < Z) {
        const int* arow = adj + (size_t)z * Z;
        float sum = 0.f; int deg = 0;
        for (int n = 0; n < Z; ++n) {
            if (arow[n] > 0) { sum += crow[n]; ++deg; }
        }
        float avg = (deg > 0) ? sum / (float)deg : 0.f;
        float c = crow[z];
        size_t idx = (size_t)b * Z + z;
        float p = preds[idx];
        float x = (c - avg) * (p - c);
        vsum = (deg > 0) ? softplus_f(x) : 0.f;
        ssum = smooth_l1_f(p - targets[idx]);
    }
    for (int o = 32; o; o >>= 1) { vsum += __shfl_down(vsum, o); ssum += __shfl_down(ssum, o); }
    __shared__ float rv[4], rs2[4];
    int lane = t & 63, wave = t >> 6;
    if (lane == 0) { rv[wave] = vsum; rs2[wave] = ssum; }
    __syncthreads();
    if (t == 0) {
        atomicAdd(&acc2[0], rv[0] + rv[1] + rv[2] + rv[3]);
        atomicAdd(&acc2[1], rs2[0] + rs2[1] + rs2[2] + rs2[3]);
    }
}

// ---------------------------------------------------------------------------
extern "C" void kernel_launch(void* const* d_in, const int* in_sizes, int n_in,
                              void* d_out, int out_size, void* d_ws, size_t ws_size,
                              hipStream_t stream) {
    const float* preds   = (const float*)d_in[0];
    const float* targets = (const float*)d_in[1];
    const float* ctemps  = (const float*)d_in[2];
    const int*   adj     = (const int*)d_in[3];
    float* out = (float*)d_out;

    long zz = in_sizes[3];
    int Z = (int)llround(sqrt((double)zz));
    int B = in_sizes[1] / Z;

    size_t off = 0;
    size_t maskOff = off; off += (size_t)Z * Z * 2;
    size_t cbfOff  = off; off += (size_t)B * Z * 2;
    size_t idgOff  = off; off += (size_t)Z * 4;
    size_t hnbOff  = off; off += (size_t)Z * 4;
    int nblk = (Z > 0 && B > 0 && (B % BM) == 0 && (Z % BN) == 0) ? (B / BM) * (Z / BN) : 0;
    size_t partOff = off; off += (size_t)(nblk > 0 ? nblk : 1) * 2 * 4;

    bool main_ok = (B % BM == 0) && (Z % BN == 0) && (Z % BK == 0) && (ws_size >= off);

    float invBZ = (float)(1.0 / ((double)B * (double)Z));

    if (main_ok) {
        char* ws = (char*)d_ws;
        unsigned short* maskbf = (unsigned short*)(ws + maskOff);
        unsigned short* cbf    = (unsigned short*)(ws + cbfOff);
        float* idg      = (float*)(ws + idgOff);
        float* hnb      = (float*)(ws + hnbOff);
        float* partials = (float*)(ws + partOff);

        k_prep<<<Z, 256, 0, stream>>>(adj, maskbf, idg, hnb, Z);
        long n8 = (long)B * Z / 8;
        k_conv<<<2048, 256, 0, stream>>>(ctemps, (uint4*)cbf, n8);
        k_gemm<<<nblk, NT, 0, stream>>>(cbf, maskbf, preds, targets, idg, hnb, partials, B, Z, Z);
        k_finalize<<<1, 256, 0, stream>>>(partials, nblk, out, invBZ);
    } else {
        float* acc2 = (float*)d_ws;
        k_zero2<<<1, 64, 0, stream>>>(acc2);
        int nzb = (Z + 255) / 256;
        k_fallback<<<B * nzb, 256, (size_t)Z * 4, stream>>>(preds, targets, ctemps, adj, acc2, B, Z);
        k_finalize<<<1, 256, 0, stream>>>(acc2, 1, out, invBZ);
    }
}

// Round 9
// 233.464 us; speedup vs baseline: 1.4798x; 1.0834x over previous
//
#include <hip/hip_runtime.h>
#include <hip/hip_bf16.h>
#include <cmath>

#define BETA 0.3f
#define LAMBDA_PHY 0.15f

#define BM 128
#define BN 128
#define BK 64
#define NT 512

typedef __bf16 bf16x8 __attribute__((ext_vector_type(8)));
typedef float f32x4 __attribute__((ext_vector_type(4)));

#define AS1 __attribute__((address_space(1)))
#define AS3 __attribute__((address_space(3)))

#define FENCE() asm volatile("" ::: "memory")
#define BARRIER() do { FENCE(); __builtin_amdgcn_s_barrier(); FENCE(); } while (0)
#define WAITV4() asm volatile("s_waitcnt vmcnt(4)" ::: "memory")
#define WAITV0() asm volatile("s_waitcnt vmcnt(0)" ::: "memory")

__device__ __forceinline__ unsigned short f2bf_rn(float f) {
    unsigned int u = __builtin_bit_cast(unsigned int, f);
    return (unsigned short)((u + 0x7FFFu + ((u >> 16) & 1u)) >> 16);
}

__device__ __forceinline__ float bf2f(unsigned short u) {
    return __builtin_bit_cast(float, (unsigned int)u << 16);
}

__device__ __forceinline__ float softplus_f(float x) {
    return fmaxf(x, 0.0f) + __logf(1.0f + __expf(-fabsf(x)));
}

__device__ __forceinline__ float smooth_l1_f(float d) {
    float ad = fabsf(d);
    return (ad < BETA) ? (0.5f / BETA) * d * d : (ad - 0.5f * BETA);
}

// ---------------------------------------------------------------------------
// Kernel 1: adjacency (int32 ZxZ) -> bf16 mask (ZxZ, K-contig) + invdeg + hasnb
__global__ void k_prep(const int* __restrict__ adj, unsigned short* __restrict__ maskbf,
                       float* __restrict__ invdeg, float* __restrict__ hasnb, int Z) {
    int z = blockIdx.x;
    int t = threadIdx.x;
    const int* row = adj + (size_t)z * Z;
    unsigned short* mrow = maskbf + (size_t)z * Z;
    int cnt = 0;
    for (int n = t; n < Z; n += blockDim.x) {
        int a = (row[n] > 0);
        mrow[n] = a ? (unsigned short)0x3F80 : (unsigned short)0;  // bf16 1.0 / 0.0
        cnt += a;
    }
    for (int o = 32; o; o >>= 1) cnt += __shfl_down(cnt, o);
    __shared__ int rs[4];
    int lane = t & 63, wave = t >> 6;
    if (lane == 0) rs[wave] = cnt;
    __syncthreads();
    if (t == 0) {
        int deg = rs[0] + rs[1] + rs[2] + rs[3];
        invdeg[z] = (deg > 0) ? 1.0f / (float)deg : 1.0f;
        hasnb[z]  = (deg > 0) ? 1.0f : 0.0f;
    }
}

// ---------------------------------------------------------------------------
// Kernel 2: fp32 -> bf16 (RN), 8 elems/thread, vectorized
__global__ void k_conv(const float* __restrict__ src, uint4* __restrict__ dst, long n8) {
    long i = (long)blockIdx.x * blockDim.x + threadIdx.x;
    long stride = (long)gridDim.x * blockDim.x;
    for (; i < n8; i += stride) {
        const float4* s = (const float4*)(src + i * 8);
        float4 a = s[0], b = s[1];
        uint4 o;
        o.x = (unsigned)f2bf_rn(a.x) | ((unsigned)f2bf_rn(a.y) << 16);
        o.y = (unsigned)f2bf_rn(a.z) | ((unsigned)f2bf_rn(a.w) << 16);
        o.z = (unsigned)f2bf_rn(b.x) | ((unsigned)f2bf_rn(b.y) << 16);
        o.w = (unsigned)f2bf_rn(b.z) | ((unsigned)f2bf_rn(b.w) << 16);
        dst[i] = o;
    }
}

// ---------------------------------------------------------------------------
// Kernel 3: 128x128 bf16 GEMM, 8 waves (2x4), per-wave 64x32 output.
// Round-8 was latency-bound (MfmaUtil 23%, occupancy 22%, nothing saturated):
// 96.5 KB LDS -> 1 block/CU -> 2 waves/SIMD, bare ds_read latency + barrier
// skew. Fix: 64 KB LDS -> 2 blocks/CU -> 4 waves/SIMD, and the two blocks'
// barrier phases interleave (one computes while the other waits).
// Registers: acc[4][2]=32 AGPR; fragments TRANSIENT per kk (af[4]+bv[2]=24)
// -> total <128, enforced by __launch_bounds__(NT,4) for 16 waves/CU.
// Counted vmcnt(4) (full-tile slack), raw barriers, T2 swizzle, T1 swizzle.
__global__ __launch_bounds__(NT, 4) void k_gemm(
    const unsigned short* __restrict__ Abf,   // [M][K] bf16 ctemps
    const unsigned short* __restrict__ Bbf,   // [N][K] bf16 mask
    const float* __restrict__ preds,
    const float* __restrict__ targets,
    const float* __restrict__ invdeg,
    const float* __restrict__ hasnb,
    float* __restrict__ partials,
    int M, int N, int K)
{
    __shared__ unsigned short As[2][BM * 64];   // 32 KB
    __shared__ unsigned short Bs[2][BN * 64];   // 32 KB

    const int nwg = gridDim.x;
    const int ob = blockIdx.x;
    const int bid = (nwg % 8 == 0) ? ((ob % 8) * (nwg / 8) + ob / 8) : ob;  // T1
    const int ntiles = N / BN;
    const int mt = bid / ntiles;
    const int nt = bid % ntiles;
    const int row0 = mt * BM;
    const int col0 = nt * BN;
    const int t = threadIdx.x;
    const int lane = t & 63;
    const int wave = t >> 6;
    const int wm = wave >> 2;             // 2x4 wave grid; per-wave 64x32 out
    const int wn = wave & 3;
    const int fr = lane & 15;
    const int fq = lane >> 4;
    const int fr7 = fr & 7;

    // staging: thread t -> row tr (+64 per chunk), 16B slot tc; source col-slot
    // pre-swizzled (T2). LDS dest t-linear. A: 2 chunks, B: 2 chunks.
    const int tr = t >> 3;                // 0..63
    const int tc = t & 7;                 // 16B slot 0..7
    const int cs = tc ^ (tr & 7);         // swizzled global col-slot

    f32x4 acc[4][2];
#pragma unroll
    for (int m = 0; m < 4; ++m)
#pragma unroll
        for (int n = 0; n < 2; ++n)
            acc[m][n] = (f32x4){0.f, 0.f, 0.f, 0.f};

    // per-thread source pointers (advance by BK per tile)
    const unsigned short* aSrc = Abf + (size_t)(row0 + tr) * K + cs * 8;
    const unsigned short* bSrc = Bbf + (size_t)(col0 + tr) * K + cs * 8;
    unsigned short* aDst = &As[0][t * 8];   // t*16 bytes
    unsigned short* bDst = &Bs[0][t * 8];

#define STAGE4(nbuf) do {                                                                    \
    unsigned short* ad_ = aDst + (nbuf) * (BM * 64);                                         \
    unsigned short* bd_ = bDst + (nbuf) * (BN * 64);                                         \
    _Pragma("unroll")                                                                        \
    for (int r_ = 0; r_ < 2; ++r_)                                                           \
        __builtin_amdgcn_global_load_lds((const AS1 void*)(aSrc + (size_t)(r_ * 64) * K),    \
                                         (AS3 void*)(ad_ + r_ * 4096), 16, 0, 0);            \
    _Pragma("unroll")                                                                        \
    for (int r_ = 0; r_ < 2; ++r_)                                                           \
        __builtin_amdgcn_global_load_lds((const AS1 void*)(bSrc + (size_t)(r_ * 64) * K),    \
                                         (AS3 void*)(bd_ + r_ * 4096), 16, 0, 0);            \
} while (0)

// per-kk transient fragments (af 16 + bv 8 regs live) -> small arch live-set
#define MFMA_TILE(buf) do {                                                                  \
    _Pragma("unroll")                                                                        \
    for (int kk_ = 0; kk_ < 2; ++kk_) {                                                      \
        bf16x8 af_[4], bv_[2];                                                               \
        _Pragma("unroll")                                                                    \
        for (int mi_ = 0; mi_ < 4; ++mi_)                                                    \
            af_[mi_] = *(const bf16x8*)&As[buf][(wm * 64 + mi_ * 16 + fr) * 64 +             \
                                               (((kk_ * 4 + fq) ^ fr7) * 8)];                \
        _Pragma("unroll")                                                                    \
        for (int ni_ = 0; ni_ < 2; ++ni_)                                                    \
            bv_[ni_] = *(const bf16x8*)&Bs[buf][(wn * 32 + ni_ * 16 + fr) * 64 +             \
                                               (((kk_ * 4 + fq) ^ fr7) * 8)];                \
        _Pragma("unroll")                                                                    \
        for (int mi_ = 0; mi_ < 4; ++mi_)                                                    \
        _Pragma("unroll")                                                                    \
        for (int ni_ = 0; ni_ < 2; ++ni_)                                                    \
            acc[mi_][ni_] = __builtin_amdgcn_mfma_f32_16x16x32_bf16(                         \
                af_[mi_], bv_[ni_], acc[mi_][ni_], 0, 0, 0);                                 \
    }                                                                                        \
} while (0)

    const int nk = K / BK;
    STAGE4(0);                       // tile 0 -> buf 0
    aSrc += BK; bSrc += BK;

    int cur = 0;
    for (int ti = 0; ti < nk; ++ti) {
        if (ti + 1 < nk) {
            STAGE4(cur ^ 1);         // tile ti+1 -> nb (free since barrier#2 of ti-1)
            aSrc += BK; bSrc += BK;
            WAITV4();                // retires tile ti's 4 loads (oldest in FIFO)
        } else {
            WAITV0();
        }
        BARRIER();                   // collective: cur fully staged for all waves
        MFMA_TILE(cur);
        BARRIER();                   // all reads of cur done before next stage
        cur ^= 1;
    }

#undef STAGE4
#undef MFMA_TILE

    // Fused epilogue. C/D frag layout: col=lane&15, row=(lane>>4)*4+reg.
    // block row = wm*64 + m*16 + fq*4 + j ; block col = wn*32 + n*16 + fr
    float vsum = 0.f, ssum = 0.f;
#pragma unroll
    for (int n = 0; n < 2; ++n) {
        const int z = col0 + wn * 32 + n * 16 + fr;
        const float idg = invdeg[z];
        const float hnb = hasnb[z];
#pragma unroll
        for (int m = 0; m < 4; ++m) {
            const int rb = row0 + wm * 64 + m * 16 + fq * 4;
#pragma unroll
            for (int j = 0; j < 4; ++j) {
                const size_t idx = (size_t)(rb + j) * N + z;
                float avg = acc[m][n][j] * idg;
                float c = bf2f(Abf[idx]);          // bf16 ctemps (saves 1/3 fetch)
                float p = preds[idx];
                float tg = targets[idx];
                float x = (c - avg) * (p - c);
                vsum += softplus_f(x) * hnb;
                ssum += smooth_l1_f(p - tg);
            }
        }
    }
    for (int o = 32; o; o >>= 1) { vsum += __shfl_down(vsum, o); ssum += __shfl_down(ssum, o); }
    __shared__ float rv[8], rsm[8];
    if (lane == 0) { rv[wave] = vsum; rsm[wave] = ssum; }
    __syncthreads();
    if (t == 0) {
        float v = 0.f, s = 0.f;
#pragma unroll
        for (int w = 0; w < 8; ++w) { v += rv[w]; s += rsm[w]; }
        partials[2 * (size_t)ob]     = v;
        partials[2 * (size_t)ob + 1] = s;
    }
}

// ---------------------------------------------------------------------------
// Kernel 4: deterministic fixed-order final reduction
__global__ void k_finalize(const float* __restrict__ partials, int nblk,
                           float* __restrict__ out, float invBZ) {
    __shared__ float sv[256], ss[256];
    int t = threadIdx.x;
    float v = 0.f, s = 0.f;
    for (int i = t; i < nblk; i += 256) { v += partials[2 * (size_t)i]; s += partials[2 * (size_t)i + 1]; }
    sv[t] = v; ss[t] = s;
    __syncthreads();
    for (int o = 128; o; o >>= 1) {
        if (t < o) { sv[t] += sv[t + o]; ss[t] += ss[t + o]; }
        __syncthreads();
    }
    if (t == 0) {
        float phys = sv[0] * invBZ;
        float pred = ss[0] * invBZ;
        out[0] = pred + LAMBDA_PHY * phys;
        out[1] = phys;
    }
}

// ---------------------------------------------------------------------------
// Fallback path (only if ws too small / odd shapes): fp32, atomics into ws[0..1]
__global__ void k_zero2(float* p) { if (threadIdx.x < 2) p[threadIdx.x] = 0.f; }

__global__ void k_fallback(const float* __restrict__ preds, const float* __restrict__ targets,
                           const float* __restrict__ ctemps, const int* __restrict__ adj,
                           float* __restrict__ acc2, int B, int Z) {
    extern __shared__ float crow[];
    int nzb = (Z + 255) / 256;
    int b = blockIdx.x / nzb;
    int zb = blockIdx.x % nzb;
    int t = threadIdx.x;
    const float* cr = ctemps + (size_t)b * Z;
    for (int n = t; n < Z; n += 256) crow[n] = cr[n];
    __syncthreads();
    int z = zb * 256 + t;
    float vsum = 0.f, ssum = 0.f;
    if (z < Z) {
        const int* arow = adj + (size_t)z * Z;
        float sum = 0.f; int deg = 0;
        for (int n = 0; n < Z; ++n) {
            if (arow[n] > 0) { sum += crow[n]; ++deg; }
        }
        float avg = (deg > 0) ? sum / (float)deg : 0.f;
        float c = crow[z];
        size_t idx = (size_t)b * Z + z;
        float p = preds[idx];
        float x = (c - avg) * (p - c);
        vsum = (deg > 0) ? softplus_f(x) : 0.f;
        ssum = smooth_l1_f(p - targets[idx]);
    }
    for (int o = 32; o; o >>= 1) { vsum += __shfl_down(vsum, o); ssum += __shfl_down(ssum, o); }
    __shared__ float rv[4], rs2[4];
    int lane = t & 63, wave = t >> 6;
    if (lane == 0) { rv[wave] = vsum; rs2[wave] = ssum; }
    __syncthreads();
    if (t == 0) {
        atomicAdd(&acc2[0], rv[0] + rv[1] + rv[2] + rv[3]);
        atomicAdd(&acc2[1], rs2[0] + rs2[1] + rs2[2] + rs2[3]);
    }
}

// ---------------------------------------------------------------------------
extern "C" void kernel_launch(void* const* d_in, const int* in_sizes, int n_in,
                              void* d_out, int out_size, void* d_ws, size_t ws_size,
                              hipStream_t stream) {
    const float* preds   = (const float*)d_in[0];
    const float* targets = (const float*)d_in[1];
    const float* ctemps  = (const float*)d_in[2];
    const int*   adj     = (const int*)d_in[3];
    float* out = (float*)d_out;

    long zz = in_sizes[3];
    int Z = (int)llround(sqrt((double)zz));
    int B = in_sizes[1] / Z;

    size_t off = 0;
    size_t maskOff = off; off += (size_t)Z * Z * 2;
    size_t cbfOff  = off; off += (size_t)B * Z * 2;
    size_t idgOff  = off; off += (size_t)Z * 4;
    size_t hnbOff  = off; off += (size_t)Z * 4;
    int nblk = (Z > 0 && B > 0 && (B % BM) == 0 && (Z % BN) == 0) ? (B / BM) * (Z / BN) : 0;
    size_t partOff = off; off += (size_t)(nblk > 0 ? nblk : 1) * 2 * 4;

    bool main_ok = (B % BM == 0) && (Z % BN == 0) && (Z % BK == 0) && (ws_size >= off);

    float invBZ = (float)(1.0 / ((double)B * (double)Z));

    if (main_ok) {
        char* ws = (char*)d_ws;
        unsigned short* maskbf = (unsigned short*)(ws + maskOff);
        unsigned short* cbf    = (unsigned short*)(ws + cbfOff);
        float* idg      = (float*)(ws + idgOff);
        float* hnb      = (float*)(ws + hnbOff);
        float* partials = (float*)(ws + partOff);

        k_prep<<<Z, 256, 0, stream>>>(adj, maskbf, idg, hnb, Z);
        long n8 = (long)B * Z / 8;
        k_conv<<<2048, 256, 0, stream>>>(ctemps, (uint4*)cbf, n8);
        k_gemm<<<nblk, NT, 0, stream>>>(cbf, maskbf, preds, targets, idg, hnb, partials, B, Z, Z);
        k_finalize<<<1, 256, 0, stream>>>(partials, nblk, out, invBZ);
    } else {
        float* acc2 = (float*)d_ws;
        k_zero2<<<1, 64, 0, stream>>>(acc2);
        int nzb = (Z + 255) / 256;
        k_fallback<<<B * nzb, 256, (size_t)Z * 4, stream>>>(preds, targets, ctemps, adj, acc2, B, Z);
        k_finalize<<<1, 256, 0, stream>>>(acc2, 1, out, invBZ);
    }
}

// Round 10
// 230.529 us; speedup vs baseline: 1.4987x; 1.0127x over previous
//
#include <hip/hip_runtime.h>
#include <hip/hip_bf16.h>
#include <cmath>

#define BETA 0.3f
#define LAMBDA_PHY 0.15f

#define BM 128
#define BN 128
#define BK 64
#define NT 512

typedef __bf16 bf16x8 __attribute__((ext_vector_type(8)));
typedef float f32x4 __attribute__((ext_vector_type(4)));

#define AS1 __attribute__((address_space(1)))
#define AS3 __attribute__((address_space(3)))

#define FENCE() asm volatile("" ::: "memory")
#define BARRIER() do { FENCE(); __builtin_amdgcn_s_barrier(); FENCE(); } while (0)
#define WAITV4() asm volatile("s_waitcnt vmcnt(4)" ::: "memory")
#define WAITV0() asm volatile("s_waitcnt vmcnt(0)" ::: "memory")

__device__ __forceinline__ unsigned short f2bf_rn(float f) {
    unsigned int u = __builtin_bit_cast(unsigned int, f);
    return (unsigned short)((u + 0x7FFFu + ((u >> 16) & 1u)) >> 16);
}

__device__ __forceinline__ float bf2f(unsigned short u) {
    return __builtin_bit_cast(float, (unsigned int)u << 16);
}

__device__ __forceinline__ float softplus_f(float x) {
    return fmaxf(x, 0.0f) + __logf(1.0f + __expf(-fabsf(x)));
}

__device__ __forceinline__ float smooth_l1_f(float d) {
    float ad = fabsf(d);
    return (ad < BETA) ? (0.5f / BETA) * d * d : (ad - 0.5f * BETA);
}

// ---------------------------------------------------------------------------
// Kernel 1: adjacency (int32 ZxZ) -> bf16 mask (ZxZ, K-contig) + invdeg + hasnb
__global__ void k_prep(const int* __restrict__ adj, unsigned short* __restrict__ maskbf,
                       float* __restrict__ invdeg, float* __restrict__ hasnb, int Z) {
    int z = blockIdx.x;
    int t = threadIdx.x;
    const int* row = adj + (size_t)z * Z;
    unsigned short* mrow = maskbf + (size_t)z * Z;
    int cnt = 0;
    for (int n = t; n < Z; n += blockDim.x) {
        int a = (row[n] > 0);
        mrow[n] = a ? (unsigned short)0x3F80 : (unsigned short)0;  // bf16 1.0 / 0.0
        cnt += a;
    }
    for (int o = 32; o; o >>= 1) cnt += __shfl_down(cnt, o);
    __shared__ int rs[4];
    int lane = t & 63, wave = t >> 6;
    if (lane == 0) rs[wave] = cnt;
    __syncthreads();
    if (t == 0) {
        int deg = rs[0] + rs[1] + rs[2] + rs[3];
        invdeg[z] = (deg > 0) ? 1.0f / (float)deg : 1.0f;
        hasnb[z]  = (deg > 0) ? 1.0f : 0.0f;
    }
}

// ---------------------------------------------------------------------------
// Kernel 2: fp32 -> bf16 (RN), 8 elems/thread, vectorized
__global__ void k_conv(const float* __restrict__ src, uint4* __restrict__ dst, long n8) {
    long i = (long)blockIdx.x * blockDim.x + threadIdx.x;
    long stride = (long)gridDim.x * blockDim.x;
    for (; i < n8; i += stride) {
        const float4* s = (const float4*)(src + i * 8);
        float4 a = s[0], b = s[1];
        uint4 o;
        o.x = (unsigned)f2bf_rn(a.x) | ((unsigned)f2bf_rn(a.y) << 16);
        o.y = (unsigned)f2bf_rn(a.z) | ((unsigned)f2bf_rn(a.w) << 16);
        o.z = (unsigned)f2bf_rn(b.x) | ((unsigned)f2bf_rn(b.y) << 16);
        o.w = (unsigned)f2bf_rn(b.z) | ((unsigned)f2bf_rn(b.w) << 16);
        dst[i] = o;
    }
}

// ---------------------------------------------------------------------------
// Kernel 3: 128x128 bf16 GEMM, 8 waves (2x4), per-wave 64x32, 2 blocks/CU.
// Round-10 changes vs round-9 (which was VALU-heavy: VALUBusy 34 > Mfma 29):
//  - K-loop unrolled 2 tiles/iter with COMPILE-TIME buffer index -> no runtime
//    `cur`; LDS read/stage addresses = 4 loop-invariant bases + offset: imms.
//  - T5 setprio around MFMA clusters (2 independent blocks/CU give the wave
//    role diversity the mechanism needs).
//  - Same counted vmcnt(4) ledger, raw barriers, T2 swizzle, T1 XCD swizzle.
__global__ __launch_bounds__(NT, 4) void k_gemm(
    const unsigned short* __restrict__ Abf,   // [M][K] bf16 ctemps
    const unsigned short* __restrict__ Bbf,   // [N][K] bf16 mask
    const float* __restrict__ preds,
    const float* __restrict__ targets,
    const float* __restrict__ invdeg,
    const float* __restrict__ hasnb,
    float* __restrict__ partials,
    int M, int N, int K)
{
    __shared__ unsigned short AsF[2 * BM * 64];   // 32 KB (buf stride 8192 elems)
    __shared__ unsigned short BsF[2 * BN * 64];   // 32 KB

    const int nwg = gridDim.x;
    const int ob = blockIdx.x;
    const int bid = (nwg % 8 == 0) ? ((ob % 8) * (nwg / 8) + ob / 8) : ob;  // T1
    const int ntiles = N / BN;
    const int mt = bid / ntiles;
    const int nt = bid % ntiles;
    const int row0 = mt * BM;
    const int col0 = nt * BN;
    const int t = threadIdx.x;
    const int lane = t & 63;
    const int wave = t >> 6;
    const int wm = wave >> 2;             // 2x4 wave grid; per-wave 64x32 out
    const int wn = wave & 3;
    const int fr = lane & 15;
    const int fq = lane >> 4;
    const int fr7 = fr & 7;

    // staging: thread t -> row tr (+64 per chunk), 16B slot tc; source col-slot
    // pre-swizzled (T2). LDS dest t-linear.
    const int tr = t >> 3;                // 0..63
    const int tc = t & 7;                 // 16B slot 0..7
    const int cs = tc ^ (tr & 7);         // swizzled global col-slot

    // loop-invariant LDS read offsets (elements); reads below use these bases
    // + compile-time immediates only (BUF*8192 + mi*1024 elems).
    const int colk0 = (fq ^ fr7) * 8;
    const int colk1 = ((4 + fq) ^ fr7) * 8;
    const int ofsA0 = (wm * 64 + fr) * 64 + colk0;
    const int ofsA1 = (wm * 64 + fr) * 64 + colk1;
    const int ofsB0 = (wn * 32 + fr) * 64 + colk0;
    const int ofsB1 = (wn * 32 + fr) * 64 + colk1;

    f32x4 acc[4][2];
#pragma unroll
    for (int m = 0; m < 4; ++m)
#pragma unroll
        for (int n = 0; n < 2; ++n)
            acc[m][n] = (f32x4){0.f, 0.f, 0.f, 0.f};

    // per-thread source pointers (advance by BK per staged tile)
    const unsigned short* aSrc = Abf + (size_t)(row0 + tr) * K + cs * 8;
    const unsigned short* bSrc = Bbf + (size_t)(col0 + tr) * K + cs * 8;
    unsigned short* aDstC = &AsF[t * 8];   // t*16 bytes within buf 0
    unsigned short* bDstC = &BsF[t * 8];

#define STAGE(BUF) do {                                                                      \
    _Pragma("unroll")                                                                        \
    for (int r_ = 0; r_ < 2; ++r_)                                                           \
        __builtin_amdgcn_global_load_lds((const AS1 void*)(aSrc + (size_t)(r_ * 64) * K),    \
                                         (AS3 void*)(aDstC + (BUF) * 8192 + r_ * 4096), 16, 0, 0); \
    _Pragma("unroll")                                                                        \
    for (int r_ = 0; r_ < 2; ++r_)                                                           \
        __builtin_amdgcn_global_load_lds((const AS1 void*)(bSrc + (size_t)(r_ * 64) * K),    \
                                         (AS3 void*)(bDstC + (BUF) * 8192 + r_ * 4096), 16, 0, 0); \
    aSrc += BK; bSrc += BK;                                                                  \
} while (0)

// One kk half-step: 6 ds_reads (offset-imm from loop-invariant bases) + 8 MFMA.
#define MFMA_KK(BUF, OFSA, OFSB) do {                                                        \
    bf16x8 af_[4], bv_[2];                                                                   \
    _Pragma("unroll")                                                                        \
    for (int mi_ = 0; mi_ < 4; ++mi_)                                                        \
        af_[mi_] = *(const bf16x8*)(AsF + (BUF) * 8192 + (OFSA) + mi_ * 1024);               \
    _Pragma("unroll")                                                                        \
    for (int ni_ = 0; ni_ < 2; ++ni_)                                                        \
        bv_[ni_] = *(const bf16x8*)(BsF + (BUF) * 8192 + (OFSB) + ni_ * 1024);               \
    __builtin_amdgcn_s_setprio(1);                                                           \
    _Pragma("unroll")                                                                        \
    for (int mi_ = 0; mi_ < 4; ++mi_)                                                        \
    _Pragma("unroll")                                                                        \
    for (int ni_ = 0; ni_ < 2; ++ni_)                                                        \
        acc[mi_][ni_] = __builtin_amdgcn_mfma_f32_16x16x32_bf16(                             \
            af_[mi_], bv_[ni_], acc[mi_][ni_], 0, 0, 0);                                     \
    __builtin_amdgcn_s_setprio(0);                                                           \
} while (0)

    const int nk = K / BK;          // even (guarded in launch)
    const int nk2 = nk >> 1;
    STAGE(0);                        // tile 0 -> buf 0

    for (int i = 0; i < nk2; ++i) {
        // half A: compute buf0 (tile 2i), stage tile 2i+1 -> buf1
        STAGE(1);
        WAITV4();                    // retires tile 2i's 4 loads (oldest)
        BARRIER();
        MFMA_KK(0, ofsA0, ofsB0);
        MFMA_KK(0, ofsA1, ofsB1);
        BARRIER();
        // half B: compute buf1 (tile 2i+1), stage tile 2i+2 -> buf0
        if (i + 1 < nk2) {
            STAGE(0);
            WAITV4();                // retires tile 2i+1's 4 loads
        } else {
            WAITV0();
        }
        BARRIER();
        MFMA_KK(1, ofsA0, ofsB0);
        MFMA_KK(1, ofsA1, ofsB1);
        BARRIER();
    }

#undef STAGE
#undef MFMA_KK

    // Fused epilogue. C/D frag layout: col=lane&15, row=(lane>>4)*4+reg.
    // block row = wm*64 + m*16 + fq*4 + j ; block col = wn*32 + n*16 + fr
    float vsum = 0.f, ssum = 0.f;
#pragma unroll
    for (int n = 0; n < 2; ++n) {
        const int z = col0 + wn * 32 + n * 16 + fr;
        const float idg = invdeg[z];
        const float hnb = hasnb[z];
#pragma unroll
        for (int m = 0; m < 4; ++m) {
            const int rb = row0 + wm * 64 + m * 16 + fq * 4;
#pragma unroll
            for (int j = 0; j < 4; ++j) {
                const size_t idx = (size_t)(rb + j) * N + z;
                float avg = acc[m][n][j] * idg;
                float c = bf2f(Abf[idx]);          // bf16 ctemps (saves 1/3 fetch)
                float p = preds[idx];
                float tg = targets[idx];
                float x = (c - avg) * (p - c);
                vsum += softplus_f(x) * hnb;
                ssum += smooth_l1_f(p - tg);
            }
        }
    }
    for (int o = 32; o; o >>= 1) { vsum += __shfl_down(vsum, o); ssum += __shfl_down(ssum, o); }
    __shared__ float rv[8], rsm[8];
    if (lane == 0) { rv[wave] = vsum; rsm[wave] = ssum; }
    __syncthreads();
    if (t == 0) {
        float v = 0.f, s = 0.f;
#pragma unroll
        for (int w = 0; w < 8; ++w) { v += rv[w]; s += rsm[w]; }
        partials[2 * (size_t)ob]     = v;
        partials[2 * (size_t)ob + 1] = s;
    }
}

// ---------------------------------------------------------------------------
// Kernel 4: deterministic fixed-order final reduction
__global__ void k_finalize(const float* __restrict__ partials, int nblk,
                           float* __restrict__ out, float invBZ) {
    __shared__ float sv[256], ss[256];
    int t = threadIdx.x;
    float v = 0.f, s = 0.f;
    for (int i = t; i < nblk; i += 256) { v += partials[2 * (size_t)i]; s += partials[2 * (size_t)i + 1]; }
    sv[t] = v; ss[t] = s;
    __syncthreads();
    for (int o = 128; o; o >>= 1) {
        if (t < o) { sv[t] += sv[t + o]; ss[t] += ss[t + o]; }
        __syncthreads();
    }
    if (t == 0) {
        float phys = sv[0] * invBZ;
        float pred = ss[0] * invBZ;
        out[0] = pred + LAMBDA_PHY * phys;
        out[1] = phys;
    }
}

// ---------------------------------------------------------------------------
// Fallback path (only if ws too small / odd shapes): fp32, atomics into ws[0..1]
__global__ void k_zero2(float* p) { if (threadIdx.x < 2) p[threadIdx.x] = 0.f; }

__global__ void k_fallback(const float* __restrict__ preds, const float* __restrict__ targets,
                           const float* __restrict__ ctemps, const int* __restrict__ adj,
                           float* __restrict__ acc2, int B, int Z) {
    extern __shared__ float crow[];
    int nzb = (Z + 255) / 256;
    int b = blockIdx.x / nzb;
    int zb = blockIdx.x % nzb;
    int t = threadIdx.x;
    const float* cr = ctemps + (size_t)b * Z;
    for (int n = t; n < Z; n += 256) crow[n] = cr[n];
    __syncthreads();
    int z = zb * 256 + t;
    float vsum = 0.f, ssum = 0.f;
    if (z < Z) {
        const int* arow = adj + (size_t)z * Z;
        float sum = 0.f; int deg = 0;
        for (int n = 0; n < Z; ++n) {
            if (arow[n] > 0) { sum += crow[n]; ++deg; }
        }
        float avg = (deg > 0) ? sum / (float)deg : 0.f;
        float c = crow[z];
        size_t idx = (size_t)b * Z + z;
        float p = preds[idx];
        float x = (c - avg) * (p - c);
        vsum = (deg > 0) ? softplus_f(x) : 0.f;
        ssum = smooth_l1_f(p - targets[idx]);
    }
    for (int o = 32; o; o >>= 1) { vsum += __shfl_down(vsum, o); ssum += __shfl_down(ssum, o); }
    __shared__ float rv[4], rs2[4];
    int lane = t & 63, wave = t >> 6;
    if (lane == 0) { rv[wave] = vsum; rs2[wave] = ssum; }
    __syncthreads();
    if (t == 0) {
        atomicAdd(&acc2[0], rv[0] + rv[1] + rv[2] + rv[3]);
        atomicAdd(&acc2[1], rs2[0] + rs2[1] + rs2[2] + rs2[3]);
    }
}

// ---------------------------------------------------------------------------
extern "C" void kernel_launch(void* const* d_in, const int* in_sizes, int n_in,
                              void* d_out, int out_size, void* d_ws, size_t ws_size,
                              hipStream_t stream) {
    const float* preds   = (const float*)d_in[0];
    const float* targets = (const float*)d_in[1];
    const float* ctemps  = (const float*)d_in[2];
    const int*   adj     = (const int*)d_in[3];
    float* out = (float*)d_out;

    long zz = in_sizes[3];
    int Z = (int)llround(sqrt((double)zz));
    int B = in_sizes[1] / Z;

    size_t off = 0;
    size_t maskOff = off; off += (size_t)Z * Z * 2;
    size_t cbfOff  = off; off += (size_t)B * Z * 2;
    size_t idgOff  = off; off += (size_t)Z * 4;
    size_t hnbOff  = off; off += (size_t)Z * 4;
    int nblk = (Z > 0 && B > 0 && (B % BM) == 0 && (Z % BN) == 0) ? (B / BM) * (Z / BN) : 0;
    size_t partOff = off; off += (size_t)(nblk > 0 ? nblk : 1) * 2 * 4;

    bool main_ok = (B % BM == 0) && (Z % BN == 0) && (Z % BK == 0) &&
                   (((Z / BK) % 2) == 0) && (ws_size >= off);

    float invBZ = (float)(1.0 / ((double)B * (double)Z));

    if (main_ok) {
        char* ws = (char*)d_ws;
        unsigned short* maskbf = (unsigned short*)(ws + maskOff);
        unsigned short* cbf    = (unsigned short*)(ws + cbfOff);
        float* idg      = (float*)(ws + idgOff);
        float* hnb      = (float*)(ws + hnbOff);
        float* partials = (float*)(ws + partOff);

        k_prep<<<Z, 256, 0, stream>>>(adj, maskbf, idg, hnb, Z);
        long n8 = (long)B * Z / 8;
        k_conv<<<2048, 256, 0, stream>>>(ctemps, (uint4*)cbf, n8);
        k_gemm<<<nblk, NT, 0, stream>>>(cbf, maskbf, preds, targets, idg, hnb, partials, B, Z, Z);
        k_finalize<<<1, 256, 0, stream>>>(partials, nblk, out, invBZ);
    } else {
        float* acc2 = (float*)d_ws;
        k_zero2<<<1, 64, 0, stream>>>(acc2);
        int nzb = (Z + 255) / 256;
        k_fallback<<<B * nzb, 256, (size_t)Z * 4, stream>>>(preds, targets, ctemps, adj, acc2, B, Z);
        k_finalize<<<1, 256, 0, stream>>>(acc2, 1, out, invBZ);
    }
}